// Round 15
// baseline (106.839 us; speedup 1.0000x reference)
//
#include <hip/hip_runtime.h>
#include <hip/hip_bf16.h>

#define D_MODEL 256
#define LQ 4800
#define NB 2
#define MROWS (NB * LQ)       // 9600
#define LN_EPS 1e-5f

typedef unsigned int u32;
typedef unsigned short u16;
typedef __attribute__((ext_vector_type(8))) short bf16x8;
typedef __attribute__((ext_vector_type(4))) float f32x4;
typedef __attribute__((ext_vector_type(2))) _Float16 f16x2;

__device__ __forceinline__ u16 f2bf(float f) {
    __hip_bfloat16 h = __float2bfloat16(f);
    return *reinterpret_cast<u16*>(&h);
}

// f16 pair dot into f32 (v_dot2_f32_f16)
__device__ __forceinline__ float dot2f16(u32 a, u32 b, float c) {
#if __has_builtin(__builtin_amdgcn_fdot2)
    return __builtin_amdgcn_fdot2(__builtin_bit_cast(f16x2, a),
                                  __builtin_bit_cast(f16x2, b), c, false);
#else
    f16x2 av = __builtin_bit_cast(f16x2, a), bv = __builtin_bit_cast(f16x2, b);
    c = fmaf((float)av.x, (float)bv.x, c);
    return fmaf((float)av.y, (float)bv.y, c);
#endif
}
__device__ __forceinline__ u32 pk_fma16(u32 a, u32 b, u32 c) {
    u32 d;
    asm("v_pk_fma_f16 %0, %1, %2, %3" : "=v"(d) : "v"(a), "v"(b), "v"(c));
    return d;
}
__device__ __forceinline__ u32 pk_add16(u32 a, u32 b) {
    u32 d;
    asm("v_pk_add_f16 %0, %1, %2" : "=v"(d) : "v"(a), "v"(b));
    return d;
}
__device__ __forceinline__ u32 pkrtz(float a, float b) {
    return __builtin_bit_cast(u32, __builtin_amdgcn_cvt_pkrtz(a, b));
}
__device__ __forceinline__ void gload_lds(const u16* src, u16* dst) {
    __builtin_amdgcn_global_load_lds(
        (const __attribute__((address_space(1))) u32*)src,
        (__attribute__((address_space(3))) u32*)dst, 16, 0, 0);
}

// ---------------------------------------------------------------------------
// Fused prep: cast x & source to bf16; transpose+cast all weights.
// grid: [0,2400) cast x, [2400,4800) cast source, [4800,7360) weight tiles.
// Wqkvt is [768][256]: rows 0..255 Wq^T, 256..511 Wk^T, 512..767 Wv^T.
// ---------------------------------------------------------------------------
__global__ __launch_bounds__(256) void prep_kernel(
    const float* __restrict__ x, const float* __restrict__ source,
    const float* __restrict__ Wq, const float* __restrict__ Wk,
    const float* __restrict__ Wv, const float* __restrict__ Wm,
    const float* __restrict__ W1, const float* __restrict__ W2,
    u16* __restrict__ xb, u16* __restrict__ sb,
    u16* __restrict__ Wqkvt, u16* __restrict__ Wmt,
    u16* __restrict__ W1t, u16* __restrict__ W2t)
{
    __shared__ float tile[16][17];
    const int t = threadIdx.x;
    int bid = blockIdx.x;

    if (bid < 4800) {
        const float* src = bid < 2400 ? x : source;
        u16* dst = bid < 2400 ? xb : sb;
        int b = bid < 2400 ? bid : bid - 2400;
        int i = (b * 256 + t) * 4;
        float4 v = *reinterpret_cast<const float4*>(src + i);
        ushort4 o; o.x = f2bf(v.x); o.y = f2bf(v.y); o.z = f2bf(v.z); o.w = f2bf(v.w);
        *reinterpret_cast<ushort4*>(dst + i) = o;
        return;
    }
    int sub = bid - 4800;
    const float* W; u16* Wt; int Nd, ldt, rowoff;
    if      (sub < 256)  { W = Wq; Wt = Wqkvt; Nd = 256; ldt = 256; rowoff = 0;   }
    else if (sub < 512)  { W = Wk; Wt = Wqkvt; Nd = 256; ldt = 256; rowoff = 256; sub -= 256; }
    else if (sub < 768)  { W = Wv; Wt = Wqkvt; Nd = 256; ldt = 256; rowoff = 512; sub -= 512; }
    else if (sub < 1024) { W = Wm; Wt = Wmt;   Nd = 256; ldt = 256; rowoff = 0;   sub -= 768; }
    else if (sub < 2048) { W = W1; Wt = W1t;   Nd = 512; ldt = 512; rowoff = 0;   sub -= 1024; }
    else                 { W = W2; Wt = W2t;   Nd = 256; ldt = 512; rowoff = 0;   sub -= 2048; }
    int ntiles = Nd >> 4;
    int tn = sub % ntiles, tk = sub / ntiles;
    int tx = t & 15, ty = t >> 4;
    tile[ty][tx] = W[(size_t)(tk * 16 + ty) * Nd + tn * 16 + tx];
    __syncthreads();
    Wt[(size_t)(rowoff + tn * 16 + ty) * ldt + tk * 16 + tx] = f2bf(tile[tx][ty]);
}

// ---------------------------------------------------------------------------
// bf16 MFMA GEMM, templated tile: C = act(A @ Bt^T). BK=32, 256 threads,
// 2x2 waves. flags: 1=relu, 2=bf16 out, 4=route by col>>8, 8=f16 out.
// (Used for the fused q|k|v projection and W1.)
// ---------------------------------------------------------------------------
template<int BM, int BN>
__global__ __launch_bounds__(256) void gemm_mfma_kernel(
    const u16* __restrict__ A0, int lda0,
    const u16* __restrict__ A1, int lda1, int splitK, int nsel,
    const u16* __restrict__ Bt, int ldb,
    void* __restrict__ Cout,
    int M, int N, int K, int flags)
{
    __shared__ __align__(16) u16 As[BM * 32];
    __shared__ __align__(16) u16 Bs[BN * 32];

    constexpr int WM = BM / 2, WN = BN / 2;
    constexpr int FI = WM / 16, FJ = WN / 16;

    const int t  = threadIdx.x;
    const int l  = t & 63;
    const int w  = t >> 6;
    const int m0 = blockIdx.y * BM;
    const int n0 = blockIdx.x * BN;
    const int wr = w >> 1, wc = w & 1;

    if (nsel && n0 >= nsel) { A0 = A1; lda0 = lda1; }

    const int srow = l >> 2;
    const int sch  = (l & 3) ^ (srow & 3);

    f32x4 acc[FI][FJ];
#pragma unroll
    for (int i = 0; i < FI; ++i)
#pragma unroll
        for (int j = 0; j < FJ; ++j) acc[i][j] = (f32x4){0.f, 0.f, 0.f, 0.f};

    for (int k0 = 0; k0 < K; k0 += 32) {
        const u16* Ap; int kk, lda;
        if (splitK && k0 >= splitK) { Ap = A1; kk = k0 - splitK; lda = lda1; }
        else                        { Ap = A0; kk = k0;          lda = lda0; }

        if (BM >= 64) {
#pragma unroll
            for (int g = 0; g < BM / 64; ++g) {
                int grp = w * (BM / 64) + g;
                int row = grp * 16 + srow;
                gload_lds(Ap + (size_t)(m0 + row) * lda + kk + sch * 8, As + grp * 512);
            }
        } else if (w < BM / 16) {
            int row = w * 16 + srow;
            gload_lds(Ap + (size_t)(m0 + row) * lda + kk + sch * 8, As + w * 512);
        }
#pragma unroll
        for (int g = 0; g < BN / 64; ++g) {
            int grp = w * (BN / 64) + g;
            int row = grp * 16 + srow;
            gload_lds(Bt + (size_t)(n0 + row) * ldb + k0 + sch * 8, Bs + grp * 512);
        }
        __syncthreads();

        const int r  = l & 15;
        const int ch = l >> 4;
        bf16x8 af[FI], bfr[FJ];
#pragma unroll
        for (int i = 0; i < FI; ++i) {
            int ar = wr * WM + i * 16 + r;
            af[i] = *(const bf16x8*)((const char*)As + ar * 64 + ((ch ^ (r & 3)) * 16));
        }
#pragma unroll
        for (int j = 0; j < FJ; ++j) {
            int br = wc * WN + j * 16 + r;
            bfr[j] = *(const bf16x8*)((const char*)Bs + br * 64 + ((ch ^ (r & 3)) * 16));
        }
#pragma unroll
        for (int i = 0; i < FI; ++i)
#pragma unroll
            for (int j = 0; j < FJ; ++j)
                acc[i][j] = __builtin_amdgcn_mfma_f32_16x16x32_bf16(af[i], bfr[j], acc[i][j], 0, 0, 0);
        __syncthreads();
    }

    const int r  = l & 15;
    const int q4 = l >> 4;
#pragma unroll
    for (int i = 0; i < FI; ++i)
#pragma unroll
        for (int j = 0; j < FJ; ++j) {
            int col = n0 + wc * WN + j * 16 + r;
#pragma unroll
            for (int reg = 0; reg < 4; ++reg) {
                int row = m0 + wr * WM + i * 16 + q4 * 4 + reg;
                float vv = acc[i][j][reg];
                if (flags & 1) vv = fmaxf(vv, 0.f);
                size_t off;
                int colw, Nw;
                if (flags & 4) { off = (size_t)(col >> 8) * M * 256; colw = col & 255; Nw = 256; }
                else           { off = 0; colw = col; Nw = N; }
                if (flags & 8) {
                    _Float16 hv = (_Float16)vv;
                    ((u16*)Cout)[off + (size_t)row * Nw + colw] = __builtin_bit_cast(u16, hv);
                } else if (flags & 2) {
                    ((u16*)Cout)[off + (size_t)row * Nw + colw] = f2bf(vv);
                } else {
                    ((float*)Cout)[off + (size_t)row * Nw + colw] = vv;
                }
            }
        }
}

// ---------------------------------------------------------------------------
// One MFMA phase of the fused tail, BM=16 rows: N = FJ*64 cols, BK=32.
// 4 waves in 1x4 layout: wave w owns cols [w*FJ*16, (w+1)*FJ*16).
// A = concat(A0, A1) along K at splitK. Bt is [N][K] row-major.
// ---------------------------------------------------------------------------
template<int FJ>
__device__ __forceinline__ void mm_loop16(
    const u16* __restrict__ A0, int lda0,
    const u16* __restrict__ A1, int lda1, int splitK,
    const u16* __restrict__ Bt, int ldb, int K, int m0,
    u16* As, u16* Bs, f32x4 (&acc)[FJ])
{
    const int t = threadIdx.x;
    const int l = t & 63, w = t >> 6;
    const int srow = l >> 2;
    const int sch  = (l & 3) ^ (srow & 3);
    const int r = l & 15, ch = l >> 4;

#pragma unroll
    for (int j = 0; j < FJ; ++j) acc[j] = (f32x4){0.f, 0.f, 0.f, 0.f};

    for (int k0 = 0; k0 < K; k0 += 32) {
        const u16* Ap; int kk, lda;
        if (splitK && k0 >= splitK) { Ap = A1; kk = k0 - splitK; lda = lda1; }
        else                        { Ap = A0; kk = k0;          lda = lda0; }
        if (w == 0)
            gload_lds(Ap + (size_t)(m0 + srow) * lda + kk + sch * 8, As);
#pragma unroll
        for (int g = 0; g < FJ; ++g) {       // N/16 groups, FJ per wave
            int grp = w * FJ + g;
            int row = grp * 16 + srow;
            gload_lds(Bt + (size_t)row * ldb + k0 + sch * 8, Bs + grp * 512);
        }
        __syncthreads();
        bf16x8 af = *(const bf16x8*)((const char*)As + r * 64 + ((ch ^ (r & 3)) * 16));
#pragma unroll
        for (int j = 0; j < FJ; ++j) {
            int br = w * (FJ * 16) + j * 16 + r;
            bf16x8 bf = *(const bf16x8*)((const char*)Bs + br * 64 + ((ch ^ (r & 3)) * 16));
            acc[j] = __builtin_amdgcn_mfma_f32_16x16x32_bf16(af, bf, acc[j], 0, 0, 0);
        }
        __syncthreads();
    }
}

// ---------------------------------------------------------------------------
// Fused tail, BM=16 (600 blocks -> 2.34 blocks/CU so staging drains overlap):
// per 16-row block: msg@Wm -> LN1 -> concat(x,.)@W1 -> relu -> @W2 -> LN2 ->
// +x -> out. Intermediates round-trip block-private L2-resident scratch.
// ---------------------------------------------------------------------------
__global__ __launch_bounds__(256) void tail_kernel(
    const u16* __restrict__ msg, const u16* __restrict__ xb,
    const float* __restrict__ x,
    const u16* __restrict__ Wmt, const u16* __restrict__ W1t,
    const u16* __restrict__ W2t,
    const float* __restrict__ g1, const float* __restrict__ b1,
    const float* __restrict__ g2, const float* __restrict__ b2,
    u16* __restrict__ msglnb, u16* __restrict__ h1b,
    float* __restrict__ out)
{
    __shared__ __align__(16) u16 As[16 * 32];
    __shared__ __align__(16) u16 Bs[512 * 32];
    __shared__ float2 red[16][4];

    const int t = threadIdx.x;
    const int l = t & 63, w = t >> 6;
    const int m0 = blockIdx.x * 16;
    const int r = l & 15, q4 = l >> 4;

    // ================= Phase A: msgln = LN1(msg @ Wm) ====================
    {
        f32x4 acc[4];
        mm_loop16<4>(msg, 256, nullptr, 0, 0, Wmt, 256, 256, m0, As, Bs, acc);

        float rs[4], rq[4];
#pragma unroll
        for (int reg = 0; reg < 4; ++reg) {
            float s = 0.f, sq = 0.f;
#pragma unroll
            for (int j = 0; j < 4; ++j) { float vv = acc[j][reg]; s += vv; sq += vv * vv; }
            rs[reg] = s; rq[reg] = sq;
        }
#pragma unroll
        for (int off = 1; off <= 8; off <<= 1)
#pragma unroll
            for (int reg = 0; reg < 4; ++reg) {
                rs[reg] += __shfl_xor(rs[reg], off);
                rq[reg] += __shfl_xor(rq[reg], off);
            }
        if (r == 0)
#pragma unroll
            for (int reg = 0; reg < 4; ++reg)
                red[q4 * 4 + reg][w] = make_float2(rs[reg], rq[reg]);
        __syncthreads();

#pragma unroll
        for (int reg = 0; reg < 4; ++reg) {
            int row = q4 * 4 + reg;
            float sum = 0.f, sq = 0.f;
#pragma unroll
            for (int u = 0; u < 4; ++u) { sum += red[row][u].x; sq += red[row][u].y; }
            float mu  = sum * 0.00390625f;
            float var = sq * 0.00390625f - mu * mu;
            float rstd = rsqrtf(var + LN_EPS);
#pragma unroll
            for (int j = 0; j < 4; ++j) {
                int col = w * 64 + j * 16 + r;
                float vv = (acc[j][reg] - mu) * rstd * g1[col] + b1[col];
                msglnb[(size_t)(m0 + row) * 256 + col] = f2bf(vv);
            }
        }
    }
    __threadfence_block();
    __syncthreads();

    // ============ Phase B: h1 = relu(concat(xb, msgln) @ W1) =============
    {
        f32x4 acc[8];
        mm_loop16<8>(xb, 256, msglnb, 256, 256, W1t, 512, 512, m0, As, Bs, acc);
#pragma unroll
        for (int j = 0; j < 8; ++j) {
            int col = w * 128 + j * 16 + r;
#pragma unroll
            for (int reg = 0; reg < 4; ++reg) {
                int row = q4 * 4 + reg;
                float vv = fmaxf(acc[j][reg], 0.f);
                h1b[(size_t)(m0 + row) * 512 + col] = f2bf(vv);
            }
        }
    }
    __threadfence_block();
    __syncthreads();

    // ============ Phase C: out = x + LN2(h1 @ W2) ========================
    {
        f32x4 acc[4];
        mm_loop16<4>(h1b, 512, nullptr, 0, 0, W2t, 512, 512, m0, As, Bs, acc);

        float rs[4], rq[4];
#pragma unroll
        for (int reg = 0; reg < 4; ++reg) {
            float s = 0.f, sq = 0.f;
#pragma unroll
            for (int j = 0; j < 4; ++j) { float vv = acc[j][reg]; s += vv; sq += vv * vv; }
            rs[reg] = s; rq[reg] = sq;
        }
#pragma unroll
        for (int off = 1; off <= 8; off <<= 1)
#pragma unroll
            for (int reg = 0; reg < 4; ++reg) {
                rs[reg] += __shfl_xor(rs[reg], off);
                rq[reg] += __shfl_xor(rq[reg], off);
            }
        __syncthreads();   // red reuse from phase A
        if (r == 0)
#pragma unroll
            for (int reg = 0; reg < 4; ++reg)
                red[q4 * 4 + reg][w] = make_float2(rs[reg], rq[reg]);
        __syncthreads();

#pragma unroll
        for (int reg = 0; reg < 4; ++reg) {
            int row = q4 * 4 + reg;
            float sum = 0.f, sq = 0.f;
#pragma unroll
            for (int u = 0; u < 4; ++u) { sum += red[row][u].x; sq += red[row][u].y; }
            float mu  = sum * 0.00390625f;
            float var = sq * 0.00390625f - mu * mu;
            float rstd = rsqrtf(var + LN_EPS);
#pragma unroll
            for (int j = 0; j < 4; ++j) {
                int col = w * 64 + j * 16 + r;
                size_t oidx = (size_t)(m0 + row) * 256 + col;
                float vv = (acc[j][reg] - mu) * rstd * g2[col] + b2[col] + x[oidx];
                out[oidx] = vv;
            }
        }
    }
}

// ---------------------------------------------------------------------------
// Gathered attention: wave = (query, head-pair), 128B oct-coalesced gathers.
// XCD batch-affinity: blocks are relabeled so XCDs 0-3 (round-robin bid%8)
// process batch-0 queries only, XCDs 4-7 batch 1 -> per-XCD L2 gather
// working set halves (4.9 MB vs 9.8 MB over a 4 MiB L2).
// ---------------------------------------------------------------------------
__global__ __launch_bounds__(256, 8) void attn_kernel(
    const u16* __restrict__ q, const u16* __restrict__ k,
    const u16* __restrict__ v, const int* __restrict__ idx,
    u16* __restrict__ msg)
{
    const int t  = threadIdx.x;
    const int l  = t & 63;
    const int hp = t >> 6;              // head-pair 0..3
    // batch-affinity block relabel (9600 = 8 * 1200, bijective)
    const int bid = blockIdx.x;
    const int x8 = bid & 7, jj = bid >> 3;
    const int qi = (x8 < 4) ? (x8 * 1200 + jj) : (LQ + (x8 - 4) * 1200 + jj);
    const int n  = qi / LQ;
    const size_t srcbase = (size_t)n * LQ * 256;   // u16 units

    const int o = l >> 3;   // key-set 0..7
    const int c = l & 7;    // 16B chunk of 128B slice

    const int* idxp = idx + (size_t)qi * 64;
    int rows[8];
#pragma unroll
    for (int i = 0; i < 8; ++i) rows[i] = idxp[i * 8 + o];   // 8-lane broadcast

    const size_t hoff = (size_t)hp * 64 + c * 8;   // u16 offset in a row

    // ---- K phase ----
    uint4 kd[8];
#pragma unroll
    for (int i = 0; i < 8; ++i)
        kd[i] = *(const uint4*)(k + srcbase + (size_t)rows[i] * 256 + hoff);
    uint4 qc = *(const uint4*)(q + (size_t)qi * 256 + hoff);

    float s[8];
#pragma unroll
    for (int i = 0; i < 8; ++i) {
        float si = 0.f;
        si = dot2f16(kd[i].x, qc.x, si);
        si = dot2f16(kd[i].y, qc.y, si);
        si = dot2f16(kd[i].z, qc.z, si);
        si = dot2f16(kd[i].w, qc.w, si);
        si += __shfl_xor(si, 1);
        si += __shfl_xor(si, 2);
        s[i] = si * 0.17677669529663687f;
    }

    // ---- V phase: kd dead; latency hides under softmax ----
    uint4 vd[8];
#pragma unroll
    for (int i = 0; i < 8; ++i)
        vd[i] = *(const uint4*)(v + srcbase + (size_t)rows[i] * 256 + hoff);

    // ---- softmax over 64 keys ----
    float mx = s[0];
#pragma unroll
    for (int i = 1; i < 8; ++i) mx = fmaxf(mx, s[i]);
    mx = fmaxf(mx, __shfl_xor(mx, 8));
    mx = fmaxf(mx, __shfl_xor(mx, 16));
    mx = fmaxf(mx, __shfl_xor(mx, 32));
    float p[8], sum = 0.f;
#pragma unroll
    for (int i = 0; i < 8; ++i) { p[i] = __expf(s[i] - mx); sum += p[i]; }
    sum += __shfl_xor(sum, 8);
    sum += __shfl_xor(sum, 16);
    sum += __shfl_xor(sum, 32);
    float inv = 1.f / sum;

    // ---- PV: 8 keys x 4 dim-pair u32s, f16 packed fma ----
    u32 A0 = 0, A1 = 0, A2 = 0, A3 = 0;
#pragma unroll
    for (int i = 0; i < 8; ++i) {
        float pi = p[i] * inv;
        u32 pp = pkrtz(pi, pi);
        A0 = pk_fma16(pp, vd[i].x, A0);
        A1 = pk_fma16(pp, vd[i].y, A1);
        A2 = pk_fma16(pp, vd[i].z, A2);
        A3 = pk_fma16(pp, vd[i].w, A3);
    }

    // ---- split-reduce over the 8 o-sets ----
    const bool ob0 = (o & 1) != 0;
    const bool ob1 = (o & 2) != 0;
    {
        u32 t0 = ob0 ? A0 : A2;
        u32 t1 = ob0 ? A1 : A3;
        t0 = __shfl_xor((int)t0, 8);
        t1 = __shfl_xor((int)t1, 8);
        A0 = pk_add16(ob0 ? A2 : A0, t0);
        A1 = pk_add16(ob0 ? A3 : A1, t1);
    }
    {
        u32 u0 = ob1 ? A0 : A1;
        u0 = __shfl_xor((int)u0, 16);
        A0 = pk_add16(ob1 ? A1 : A0, u0);
    }
    A0 = pk_add16(A0, (u32)__shfl_xor((int)A0, 32));

    if (o < 4) {
        int j = 2 * (o & 1) + ((o >> 1) & 1);
        f16x2 hv = __builtin_bit_cast(f16x2, A0);
        u32 packed = (u32)f2bf((float)hv.x) | ((u32)f2bf((float)hv.y) << 16);
        *(u32*)(msg + (size_t)qi * 256 + hp * 64 + c * 8 + j * 2) = packed;
    }
}

// ---------------------------------------------------------------------------
extern "C" void kernel_launch(void* const* d_in, const int* in_sizes, int n_in,
                              void* d_out, int out_size, void* d_ws, size_t ws_size,
                              hipStream_t stream)
{
    const float* x      = (const float*)d_in[0];
    const float* source = (const float*)d_in[1];
    const int*   eidx   = (const int*)d_in[2];
    const float* Wq     = (const float*)d_in[3];
    const float* Wk     = (const float*)d_in[4];
    const float* Wv     = (const float*)d_in[5];
    const float* Wm     = (const float*)d_in[6];
    const float* W1     = (const float*)d_in[7];
    const float* W2     = (const float*)d_in[8];
    const float* g1     = (const float*)d_in[9];
    const float* b1     = (const float*)d_in[10];
    const float* g2     = (const float*)d_in[11];
    const float* b2     = (const float*)d_in[12];
    float* out = (float*)d_out;

    char* ws = (char*)d_ws;
    const size_t SZB = (size_t)MROWS * 256 * 2;    // 4.9 MB
    u16* xb     = (u16*)(ws);                      // bf16, live until tail
    u16* sb     = (u16*)(ws + SZB);                // bf16, dead after qkv gemm
    u16* qb     = (u16*)(ws + 2 * SZB);            // f16, qkv gemm seg 0
    u16* kb     = (u16*)(ws + 3 * SZB);            // f16, seg 1
    u16* vb     = (u16*)(ws + 4 * SZB);            // f16, seg 2
    u16* msgb   = (u16*)(ws + 5 * SZB);            // bf16 attn output
    u16* msglnb = (u16*)(ws + 6 * SZB);            // bf16 tail scratch
    u16* h1b    = (u16*)(ws + 7 * SZB);            // bf16 [9600][512] tail scratch
    u16* Wqkvt  = (u16*)(ws + 9 * SZB);            // [768][256]
    u16* Wmt    = Wqkvt + 768 * 256;
    u16* W1t    = Wmt + 256 * 256;                 // [512][512]
    u16* W2t    = W1t + 512 * 512;                 // [256][512]

    dim3 blk(256);

    // fused prep: casts + all weight transposes
    prep_kernel<<<dim3(7360), blk, 0, stream>>>(x, source, Wq, Wk, Wv, Wm, W1, W2,
                                                xb, sb, Wqkvt, Wmt, W1t, W2t);

    // fused q|k|v projection, f16 out, 64x128 tiles (900 blocks)
    gemm_mfma_kernel<64, 128><<<dim3(6, 150), blk, 0, stream>>>(
        xb, 256, sb, 256, 0, 256, Wqkvt, 256, qb, MROWS, 768, 256, 8 | 4);

    // gathered attention -> msg (bf16); one block per query, XCD-affine
    attn_kernel<<<dim3(MROWS), blk, 0, stream>>>(qb, kb, vb, eidx, msgb);

    // fused tail: Wm+LN1+W1+relu+W2+LN2+residual, 600 blocks of 16 rows
    tail_kernel<<<dim3(600), blk, 0, stream>>>(
        msgb, xb, x, Wmt, W1t, W2t, g1, b1, g2, b2, msglnb, h1b, out);
}

// Round 16
// 97.757 us; speedup vs baseline: 1.0929x; 1.0929x over previous
//
#include <hip/hip_runtime.h>
#include <hip/hip_bf16.h>

#define D_MODEL 256
#define LQ 4800
#define NB 2
#define MROWS (NB * LQ)       // 9600
#define LN_EPS 1e-5f

typedef unsigned int u32;
typedef unsigned short u16;
typedef __attribute__((ext_vector_type(8))) short bf16x8;
typedef __attribute__((ext_vector_type(4))) float f32x4;
typedef __attribute__((ext_vector_type(4))) u32 u32x4;
typedef __attribute__((ext_vector_type(2))) _Float16 f16x2;
typedef __attribute__((ext_vector_type(8))) _Float16 f16x8;

__device__ __forceinline__ u16 f2bf(float f) {
    __hip_bfloat16 h = __float2bfloat16(f);
    return *reinterpret_cast<u16*>(&h);
}
__device__ __forceinline__ float bf2f(u32 bits16) {
    return __uint_as_float(bits16 << 16);
}

// f16 pair dot into f32 (v_dot2_f32_f16)
__device__ __forceinline__ float dot2f16(u32 a, u32 b, float c) {
#if __has_builtin(__builtin_amdgcn_fdot2)
    return __builtin_amdgcn_fdot2(__builtin_bit_cast(f16x2, a),
                                  __builtin_bit_cast(f16x2, b), c, false);
#else
    f16x2 av = __builtin_bit_cast(f16x2, a), bv = __builtin_bit_cast(f16x2, b);
    c = fmaf((float)av.x, (float)bv.x, c);
    return fmaf((float)av.y, (float)bv.y, c);
#endif
}
__device__ __forceinline__ u32 pk_fma16(u32 a, u32 b, u32 c) {
    u32 d;
    asm("v_pk_fma_f16 %0, %1, %2, %3" : "=v"(d) : "v"(a), "v"(b), "v"(c));
    return d;
}
__device__ __forceinline__ u32 pk_add16(u32 a, u32 b) {
    u32 d;
    asm("v_pk_add_f16 %0, %1, %2" : "=v"(d) : "v"(a), "v"(b));
    return d;
}
__device__ __forceinline__ u32 pkrtz(float a, float b) {
    return __builtin_bit_cast(u32, __builtin_amdgcn_cvt_pkrtz(a, b));
}
__device__ __forceinline__ void gload_lds(const u16* src, u16* dst) {
    __builtin_amdgcn_global_load_lds(
        (const __attribute__((address_space(1))) u32*)src,
        (__attribute__((address_space(3))) u32*)dst, 16, 0, 0);
}
__device__ __forceinline__ void gload_lds_f32(const float* src, u32* dst) {
    __builtin_amdgcn_global_load_lds(
        (const __attribute__((address_space(1))) u32*)src,
        (__attribute__((address_space(3))) u32*)dst, 16, 0, 0);
}

// ---------------------------------------------------------------------------
// Prep v2: weight transposes only (x/source casts eliminated — qkv reads fp32).
// grid 2560. Layout:
//  [0,768)    Wq|Wk|Wv -> Wqkvh (f16) rows 0..767
//  [768,1024) Wm -> Wmt (bf16)
//  [1024,2048) W1: k<256 half -> Wqkvh (f16) rows 768..1279; k>=256 -> W1bt bf16
//  [2048,2560) W2 -> W2t (bf16, ldt 512)
// ---------------------------------------------------------------------------
__global__ __launch_bounds__(256) void prep_kernel(
    const float* __restrict__ Wq, const float* __restrict__ Wk,
    const float* __restrict__ Wv, const float* __restrict__ Wm,
    const float* __restrict__ W1, const float* __restrict__ W2,
    u16* __restrict__ Wqkvh, u16* __restrict__ Wmt,
    u16* __restrict__ W1bt, u16* __restrict__ W2t)
{
    __shared__ float tile[16][17];
    const int t = threadIdx.x, tx = t & 15, ty = t >> 4;
    int sub = blockIdx.x;

    const float* W; int Nd, tn, tk, drow, dcol, ldt; u16* dst; bool f16o = false;
    if (sub < 768) {
        W = sub < 256 ? Wq : (sub < 512 ? Wk : Wv);
        int s = sub & 255; Nd = 256; tn = s % 16; tk = s / 16;
        dst = Wqkvh; drow = (sub >> 8) * 256 + tn * 16; dcol = tk * 16; ldt = 256; f16o = true;
    } else if (sub < 1024) {
        W = Wm; int s = sub - 768; Nd = 256; tn = s % 16; tk = s / 16;
        dst = Wmt; drow = tn * 16; dcol = tk * 16; ldt = 256;
    } else if (sub < 2048) {
        W = W1; int s = sub - 1024; Nd = 512; tn = s % 32; tk = s / 32;
        if (tk < 16) { dst = Wqkvh; drow = 768 + tn * 16; dcol = tk * 16; ldt = 256; f16o = true; }
        else         { dst = W1bt;  drow = tn * 16; dcol = (tk - 16) * 16; ldt = 256; }
    } else {
        W = W2; int s = sub - 2048; Nd = 256; tn = s % 16; tk = s / 16;
        dst = W2t; drow = tn * 16; dcol = tk * 16; ldt = 512;
    }
    tile[ty][tx] = W[(size_t)(tk * 16 + ty) * Nd + tn * 16 + tx];
    __syncthreads();
    float v = tile[tx][ty];
    u16 o;
    if (f16o) { _Float16 h = (_Float16)v; o = __builtin_bit_cast(u16, h); }
    else      o = f2bf(v);
    dst[(size_t)(drow + ty) * ldt + dcol + tx] = o;
}

// ---------------------------------------------------------------------------
// qkv+h_top GEMM: [q|k|v|h_top] = A_fp32 @ Wqkvh^T (f16 MFMA, K=256, N=1280).
// A select by col: [0,256) x, [256,768) source, [768,1280) x.
// BM=64 x BN=128, 4 waves 2x2, FI=2, FJ=4. A staged fp32 into LDS via
// global_load_lds with XOR-8 chunk swizzle (reads <=2-way conflicts), then
// converted per-fragment with cvt_pkrtz to f16.
// Epilogue: col<768 -> f16 q/k/v buffers; col>=768 -> bf16 hx[M][512].
// ---------------------------------------------------------------------------
__global__ __launch_bounds__(256) void qkvh_kernel(
    const float* __restrict__ x, const float* __restrict__ source,
    const u16* __restrict__ Wqkvh,
    u16* __restrict__ qkvb, u16* __restrict__ hx)
{
    __shared__ __align__(16) float As32[64 * 32];   // 8 KB
    __shared__ __align__(16) u16 Bs[128 * 32];      // 8 KB

    const int t = threadIdx.x, l = t & 63, w = t >> 6;
    const int m0 = blockIdx.y * 64, n0 = blockIdx.x * 128;
    const int wr = w >> 1, wc = w & 1;
    const float* Ap = (n0 < 256 || n0 >= 768) ? x : source;

    const int srow = l >> 2, sch = (l & 3) ^ (srow & 3);   // B staging
    const int arow8 = l >> 3, acw = (l & 7) ^ (arow8 & 7); // A staging (fp32)
    const int r = l & 15, ch = l >> 4;

    f32x4 acc[2][4];
#pragma unroll
    for (int i = 0; i < 2; ++i)
#pragma unroll
        for (int j = 0; j < 4; ++j) acc[i][j] = (f32x4){0.f, 0.f, 0.f, 0.f};

    for (int k0 = 0; k0 < 256; k0 += 32) {
        // A: wave w stages rows [w*16, w*16+16) in 2 calls of 8 rows x 128B
#pragma unroll
        for (int h = 0; h < 2; ++h) {
            const float* asrc = Ap + (size_t)(m0 + w * 16 + h * 8 + arow8) * 256 + k0 + acw * 4;
            u32* adst = (u32*)As32 + w * 512 + h * 256;
            gload_lds_f32(asrc, adst);
        }
        // B: 8 groups of 16 rows, 2 per wave
#pragma unroll
        for (int g = 0; g < 2; ++g) {
            int grp = w * 2 + g;
            gload_lds(Wqkvh + (size_t)(n0 + grp * 16 + srow) * 256 + k0 + sch * 8,
                      Bs + grp * 512);
        }
        __syncthreads();

        f16x8 af[2];
#pragma unroll
        for (int i = 0; i < 2; ++i) {
            int ar = wr * 32 + i * 16 + r;
            int s0 = (2 * ch) ^ (ar & 7), s1 = (2 * ch + 1) ^ (ar & 7);
            f32x4 alo = *(const f32x4*)((const char*)As32 + ar * 128 + s0 * 16);
            f32x4 ahi = *(const f32x4*)((const char*)As32 + ar * 128 + s1 * 16);
            u32x4 pk = { pkrtz(alo.x, alo.y), pkrtz(alo.z, alo.w),
                         pkrtz(ahi.x, ahi.y), pkrtz(ahi.z, ahi.w) };
            af[i] = __builtin_bit_cast(f16x8, pk);
        }
#pragma unroll
        for (int j = 0; j < 4; ++j) {
            int br = wc * 64 + j * 16 + r;
            f16x8 bf = *(const f16x8*)((const char*)Bs + br * 64 + ((ch ^ (r & 3)) * 16));
#pragma unroll
            for (int i = 0; i < 2; ++i)
                acc[i][j] = __builtin_amdgcn_mfma_f32_16x16x32_f16(af[i], bf, acc[i][j], 0, 0, 0);
        }
        __syncthreads();
    }

    const int q4 = l >> 4;
#pragma unroll
    for (int i = 0; i < 2; ++i)
#pragma unroll
        for (int j = 0; j < 4; ++j) {
            int col = n0 + wc * 64 + j * 16 + r;
#pragma unroll
            for (int reg = 0; reg < 4; ++reg) {
                int row = m0 + wr * 32 + i * 16 + q4 * 4 + reg;
                float vv = acc[i][j][reg];
                if (col < 768) {
                    _Float16 hv = (_Float16)vv;
                    qkvb[(size_t)(col >> 8) * MROWS * 256 + (size_t)row * 256 + (col & 255)] =
                        __builtin_bit_cast(u16, hv);
                } else {
                    hx[(size_t)row * 512 + (col - 768)] = f2bf(vv);
                }
            }
        }
}

// ---------------------------------------------------------------------------
// Fused Wm+LN1+W1_bot: per 32-row block (300 blocks):
// Phase A: msgln = LN1(msg @ Wm)  (K=256), kept in LDS (swizzled) — no global.
// Phase B: h1 = relu(msgln @ W1_bot + hx)  (K=256), A from LDS (no staging).
// ---------------------------------------------------------------------------
__global__ __launch_bounds__(256) void wm_w1_kernel(
    const u16* __restrict__ msg, const u16* __restrict__ Wmt,
    const u16* __restrict__ W1bt, const u16* __restrict__ hx,
    const float* __restrict__ g1, const float* __restrict__ b1,
    u16* __restrict__ h1b)
{
    __shared__ __align__(16) u16 As[32 * 32];      // 2 KB
    __shared__ __align__(16) u16 Bs[512 * 32];     // 32 KB
    __shared__ __align__(16) u16 mln[32 * 256];    // 16 KB, XOR-8 swizzled
    __shared__ float2 red[32][2];

    const int t = threadIdx.x, l = t & 63, w = t >> 6;
    const int m0 = blockIdx.x * 32;
    const int srow = l >> 2, sch = (l & 3) ^ (srow & 3);
    const int r = l & 15, ch = l >> 4, q4 = l >> 4;

    // ================= Phase A (2x2 waves, FJ=8) =========================
    {
        const int wr = w >> 1, wc = w & 1;
        f32x4 acc[8];
#pragma unroll
        for (int j = 0; j < 8; ++j) acc[j] = (f32x4){0.f, 0.f, 0.f, 0.f};

        for (int k0 = 0; k0 < 256; k0 += 32) {
            if (w < 2)
                gload_lds(msg + (size_t)(m0 + w * 16 + srow) * 256 + k0 + sch * 8, As + w * 512);
#pragma unroll
            for (int g = 0; g < 4; ++g) {
                int grp = w * 4 + g;
                gload_lds(Wmt + (size_t)(grp * 16 + srow) * 256 + k0 + sch * 8, Bs + grp * 512);
            }
            __syncthreads();
            bf16x8 af = *(const bf16x8*)((const char*)As + (wr * 16 + r) * 64 + ((ch ^ (r & 3)) * 16));
#pragma unroll
            for (int j = 0; j < 8; ++j) {
                int br = wc * 128 + j * 16 + r;
                bf16x8 bf = *(const bf16x8*)((const char*)Bs + br * 64 + ((ch ^ (r & 3)) * 16));
                acc[j] = __builtin_amdgcn_mfma_f32_16x16x32_bf16(af, bf, acc[j], 0, 0, 0);
            }
            __syncthreads();
        }

        float rs[4], rq[4];
#pragma unroll
        for (int reg = 0; reg < 4; ++reg) {
            float s = 0.f, sq = 0.f;
#pragma unroll
            for (int j = 0; j < 8; ++j) { float vv = acc[j][reg]; s += vv; sq += vv * vv; }
            rs[reg] = s; rq[reg] = sq;
        }
#pragma unroll
        for (int off = 1; off <= 8; off <<= 1)
#pragma unroll
            for (int reg = 0; reg < 4; ++reg) {
                rs[reg] += __shfl_xor(rs[reg], off);
                rq[reg] += __shfl_xor(rq[reg], off);
            }
        if (r == 0)
#pragma unroll
            for (int reg = 0; reg < 4; ++reg)
                red[wr * 16 + q4 * 4 + reg][wc] = make_float2(rs[reg], rq[reg]);
        __syncthreads();

#pragma unroll
        for (int reg = 0; reg < 4; ++reg) {
            int row = wr * 16 + q4 * 4 + reg;
            float sum = red[row][0].x + red[row][1].x;
            float sq  = red[row][0].y + red[row][1].y;
            float mu  = sum * 0.00390625f;
            float var = sq * 0.00390625f - mu * mu;
            float rstd = rsqrtf(var + LN_EPS);
#pragma unroll
            for (int j = 0; j < 8; ++j) {
                int col = wc * 128 + j * 16 + r;
                float vv = (acc[j][reg] - mu) * rstd * g1[col] + b1[col];
                int cc = col >> 3, slot = cc ^ (row & 7);
                *(u16*)((char*)mln + row * 512 + slot * 16 + (col & 7) * 2) = f2bf(vv);
            }
        }
        __syncthreads();
    }

    // ================= Phase B (1x4 waves, FI=2, FJ=8) ===================
    {
        f32x4 acc2[2][8];
#pragma unroll
        for (int i = 0; i < 2; ++i)
#pragma unroll
            for (int j = 0; j < 8; ++j) acc2[i][j] = (f32x4){0.f, 0.f, 0.f, 0.f};

        for (int k0 = 0; k0 < 256; k0 += 32) {
#pragma unroll
            for (int g = 0; g < 8; ++g) {
                int row = w * 128 + g * 16 + srow;
                gload_lds(W1bt + (size_t)row * 256 + k0 + sch * 8, Bs + (w * 8 + g) * 512);
            }
            __syncthreads();
            bf16x8 af2[2];
#pragma unroll
            for (int i = 0; i < 2; ++i) {
                int ar = i * 16 + r;
                int c0 = (k0 >> 3) + ch;
                af2[i] = *(const bf16x8*)((const char*)mln + ar * 512 + ((c0 ^ (ar & 7)) * 16));
            }
#pragma unroll
            for (int j = 0; j < 8; ++j) {
                int br = w * 128 + j * 16 + r;
                bf16x8 bf = *(const bf16x8*)((const char*)Bs + br * 64 + ((ch ^ (r & 3)) * 16));
#pragma unroll
                for (int i = 0; i < 2; ++i)
                    acc2[i][j] = __builtin_amdgcn_mfma_f32_16x16x32_bf16(af2[i], bf, acc2[i][j], 0, 0, 0);
            }
            __syncthreads();
        }

#pragma unroll
        for (int i = 0; i < 2; ++i)
#pragma unroll
            for (int j = 0; j < 8; ++j) {
                int col = w * 128 + j * 16 + r;
#pragma unroll
                for (int reg = 0; reg < 4; ++reg) {
                    int row = i * 16 + q4 * 4 + reg;
                    size_t oidx = (size_t)(m0 + row) * 512 + col;
                    float vv = acc2[i][j][reg] + bf2f((u32)hx[oidx]);
                    vv = fmaxf(vv, 0.f);
                    h1b[oidx] = f2bf(vv);
                }
            }
    }
}

// ---------------------------------------------------------------------------
// GEMM (BM rows, N=256) with fused LayerNorm epilogue (for W2+LN2+residual).
// ---------------------------------------------------------------------------
template<int BM, bool RESID, bool OUT_BF16>
__global__ __launch_bounds__(256) void gemm_ln_kernel(
    const u16* __restrict__ A, int lda,
    const u16* __restrict__ Bt, int ldb,
    const float* __restrict__ g, const float* __restrict__ b,
    const float* __restrict__ xres,
    void* __restrict__ Cout, int K)
{
    constexpr int WAVES_M = BM / 16;
    constexpr int WAVES_N = 4 / WAVES_M;
    constexpr int WN = 256 / WAVES_N;
    constexpr int FJ = WN / 16;

    __shared__ __align__(16) u16 As[BM * 32];
    __shared__ __align__(16) u16 Bs[256 * 32];
    __shared__ float2 red[BM][WAVES_N];

    const int t  = threadIdx.x;
    const int l  = t & 63;
    const int w  = t >> 6;
    const int m0 = blockIdx.x * BM;
    const int wr = w / WAVES_N, wc = w % WAVES_N;

    const int srow = l >> 2;
    const int sch  = (l & 3) ^ (srow & 3);

    f32x4 acc[FJ];
#pragma unroll
    for (int j = 0; j < FJ; ++j) acc[j] = (f32x4){0.f, 0.f, 0.f, 0.f};

    for (int k0 = 0; k0 < K; k0 += 32) {
        if (w < WAVES_M) {
            int row = w * 16 + srow;
            gload_lds(A + (size_t)(m0 + row) * lda + k0 + sch * 8, As + w * 512);
        }
#pragma unroll
        for (int gg = 0; gg < 4; ++gg) {
            int grp = w * 4 + gg;
            int row = grp * 16 + srow;
            gload_lds(Bt + (size_t)row * ldb + k0 + sch * 8, Bs + grp * 512);
        }
        __syncthreads();

        const int r  = l & 15;
        const int ch = l >> 4;
        bf16x8 af = *(const bf16x8*)((const char*)As + (wr * 16 + r) * 64 + ((ch ^ (r & 3)) * 16));
#pragma unroll
        for (int j = 0; j < FJ; ++j) {
            int br = wc * WN + j * 16 + r;
            bf16x8 bf = *(const bf16x8*)((const char*)Bs + br * 64 + ((ch ^ (r & 3)) * 16));
            acc[j] = __builtin_amdgcn_mfma_f32_16x16x32_bf16(af, bf, acc[j], 0, 0, 0);
        }
        __syncthreads();
    }

    const int r  = l & 15;
    const int q4 = l >> 4;

    float rs[4], rq[4];
#pragma unroll
    for (int reg = 0; reg < 4; ++reg) {
        float s = 0.f, sq = 0.f;
#pragma unroll
        for (int j = 0; j < FJ; ++j) { float vv = acc[j][reg]; s += vv; sq += vv * vv; }
        rs[reg] = s; rq[reg] = sq;
    }
#pragma unroll
    for (int off = 1; off <= 8; off <<= 1)
#pragma unroll
        for (int reg = 0; reg < 4; ++reg) {
            rs[reg] += __shfl_xor(rs[reg], off);
            rq[reg] += __shfl_xor(rq[reg], off);
        }
    if (r == 0)
#pragma unroll
        for (int reg = 0; reg < 4; ++reg)
            red[wr * 16 + q4 * 4 + reg][wc] = make_float2(rs[reg], rq[reg]);
    __syncthreads();

    float gj[FJ], bj[FJ];
#pragma unroll
    for (int j = 0; j < FJ; ++j) {
        int col = wc * WN + j * 16 + r;
        gj[j] = g[col]; bj[j] = b[col];
    }

#pragma unroll
    for (int reg = 0; reg < 4; ++reg) {
        int row = wr * 16 + q4 * 4 + reg;
        float sum = 0.f, sq = 0.f;
#pragma unroll
        for (int u = 0; u < WAVES_N; ++u) { sum += red[row][u].x; sq += red[row][u].y; }
        float mu  = sum * 0.00390625f;
        float var = sq * 0.00390625f - mu * mu;
        float rstd = rsqrtf(var + LN_EPS);
#pragma unroll
        for (int j = 0; j < FJ; ++j) {
            int col = wc * WN + j * 16 + r;
            float vv = (acc[j][reg] - mu) * rstd * gj[j] + bj[j];
            size_t oidx = (size_t)(m0 + row) * 256 + col;
            if (RESID) vv += xres[oidx];
            if (OUT_BF16) ((u16*)Cout)[oidx] = f2bf(vv);
            else          ((float*)Cout)[oidx] = vv;
        }
    }
}

// ---------------------------------------------------------------------------
// Gathered attention: wave = (query, head-pair), 128B oct-coalesced gathers.
// XCD batch-affinity relabel. At the random-gather L2 floor (~34 us).
// ---------------------------------------------------------------------------
__global__ __launch_bounds__(256, 8) void attn_kernel(
    const u16* __restrict__ q, const u16* __restrict__ k,
    const u16* __restrict__ v, const int* __restrict__ idx,
    u16* __restrict__ msg)
{
    const int t  = threadIdx.x;
    const int l  = t & 63;
    const int hp = t >> 6;
    const int bid = blockIdx.x;
    const int x8 = bid & 7, jj = bid >> 3;
    const int qi = (x8 < 4) ? (x8 * 1200 + jj) : (LQ + (x8 - 4) * 1200 + jj);
    const int n  = qi / LQ;
    const size_t srcbase = (size_t)n * LQ * 256;

    const int o = l >> 3;
    const int c = l & 7;

    const int* idxp = idx + (size_t)qi * 64;
    int rows[8];
#pragma unroll
    for (int i = 0; i < 8; ++i) rows[i] = idxp[i * 8 + o];

    const size_t hoff = (size_t)hp * 64 + c * 8;

    uint4 kd[8];
#pragma unroll
    for (int i = 0; i < 8; ++i)
        kd[i] = *(const uint4*)(k + srcbase + (size_t)rows[i] * 256 + hoff);
    uint4 qc = *(const uint4*)(q + (size_t)qi * 256 + hoff);

    float s[8];
#pragma unroll
    for (int i = 0; i < 8; ++i) {
        float si = 0.f;
        si = dot2f16(kd[i].x, qc.x, si);
        si = dot2f16(kd[i].y, qc.y, si);
        si = dot2f16(kd[i].z, qc.z, si);
        si = dot2f16(kd[i].w, qc.w, si);
        si += __shfl_xor(si, 1);
        si += __shfl_xor(si, 2);
        s[i] = si * 0.17677669529663687f;
    }

    uint4 vd[8];
#pragma unroll
    for (int i = 0; i < 8; ++i)
        vd[i] = *(const uint4*)(v + srcbase + (size_t)rows[i] * 256 + hoff);

    float mx = s[0];
#pragma unroll
    for (int i = 1; i < 8; ++i) mx = fmaxf(mx, s[i]);
    mx = fmaxf(mx, __shfl_xor(mx, 8));
    mx = fmaxf(mx, __shfl_xor(mx, 16));
    mx = fmaxf(mx, __shfl_xor(mx, 32));
    float p[8], sum = 0.f;
#pragma unroll
    for (int i = 0; i < 8; ++i) { p[i] = __expf(s[i] - mx); sum += p[i]; }
    sum += __shfl_xor(sum, 8);
    sum += __shfl_xor(sum, 16);
    sum += __shfl_xor(sum, 32);
    float inv = 1.f / sum;

    u32 A0 = 0, A1 = 0, A2 = 0, A3 = 0;
#pragma unroll
    for (int i = 0; i < 8; ++i) {
        float pi = p[i] * inv;
        u32 pp = pkrtz(pi, pi);
        A0 = pk_fma16(pp, vd[i].x, A0);
        A1 = pk_fma16(pp, vd[i].y, A1);
        A2 = pk_fma16(pp, vd[i].z, A2);
        A3 = pk_fma16(pp, vd[i].w, A3);
    }

    const bool ob0 = (o & 1) != 0;
    const bool ob1 = (o & 2) != 0;
    {
        u32 t0 = ob0 ? A0 : A2;
        u32 t1 = ob0 ? A1 : A3;
        t0 = __shfl_xor((int)t0, 8);
        t1 = __shfl_xor((int)t1, 8);
        A0 = pk_add16(ob0 ? A2 : A0, t0);
        A1 = pk_add16(ob0 ? A3 : A1, t1);
    }
    {
        u32 u0 = ob1 ? A0 : A1;
        u0 = __shfl_xor((int)u0, 16);
        A0 = pk_add16(ob1 ? A1 : A0, u0);
    }
    A0 = pk_add16(A0, (u32)__shfl_xor((int)A0, 32));

    if (o < 4) {
        int j = 2 * (o & 1) + ((o >> 1) & 1);
        f16x2 hv = __builtin_bit_cast(f16x2, A0);
        u32 packed = (u32)f2bf((float)hv.x) | ((u32)f2bf((float)hv.y) << 16);
        *(u32*)(msg + (size_t)qi * 256 + hp * 64 + c * 8 + j * 2) = packed;
    }
}

// ---------------------------------------------------------------------------
extern "C" void kernel_launch(void* const* d_in, const int* in_sizes, int n_in,
                              void* d_out, int out_size, void* d_ws, size_t ws_size,
                              hipStream_t stream)
{
    const float* x      = (const float*)d_in[0];
    const float* source = (const float*)d_in[1];
    const int*   eidx   = (const int*)d_in[2];
    const float* Wq     = (const float*)d_in[3];
    const float* Wk     = (const float*)d_in[4];
    const float* Wv     = (const float*)d_in[5];
    const float* Wm     = (const float*)d_in[6];
    const float* W1     = (const float*)d_in[7];
    const float* W2     = (const float*)d_in[8];
    const float* g1     = (const float*)d_in[9];
    const float* b1     = (const float*)d_in[10];
    const float* g2     = (const float*)d_in[11];
    const float* b2     = (const float*)d_in[12];
    float* out = (float*)d_out;

    char* ws = (char*)d_ws;
    const size_t SZB = (size_t)MROWS * 256 * 2;    // 4.9 MB
    u16* qb     = (u16*)(ws);                      // f16 q
    u16* kb     = (u16*)(ws + SZB);                // f16 k
    u16* vb     = (u16*)(ws + 2 * SZB);            // f16 v
    u16* msgb   = (u16*)(ws + 3 * SZB);            // bf16 attn output
    u16* hx     = (u16*)(ws + 4 * SZB);            // bf16 [9600][512] x@W1_top
    u16* h1b    = (u16*)(ws + 6 * SZB);            // bf16 [9600][512]
    u16* Wqkvh  = (u16*)(ws + 8 * SZB);            // f16 [1280][256]
    u16* Wmt    = Wqkvh + 1280 * 256;              // bf16 [256][256]
    u16* W1bt   = Wmt + 256 * 256;                 // bf16 [512][256]
    u16* W2t    = W1bt + 512 * 256;                // bf16 [256][512]

    dim3 blk(256);

    // weight transposes only
    prep_kernel<<<dim3(2560), blk, 0, stream>>>(Wq, Wk, Wv, Wm, W1, W2,
                                                Wqkvh, Wmt, W1bt, W2t);

    // q|k|v|h_top from fp32 inputs (f16 MFMA), N=1280, 1500 blocks
    qkvh_kernel<<<dim3(10, 150), blk, 0, stream>>>(x, source, Wqkvh, qb, hx);

    // gathered attention -> msg (bf16)
    attn_kernel<<<dim3(MROWS), blk, 0, stream>>>(qb, kb, vb, eidx, msgb);

    // Wm+LN1+W1_bot fused (msgln stays in LDS) -> h1b
    wm_w1_kernel<<<dim3(300), blk, 0, stream>>>(msgb, Wmt, W1bt, hx, g1, b1, h1b);

    // h1 @ W2 + LN2 + residual -> fp32 out
    gemm_ln_kernel<32, true, false><<<dim3(300), blk, 0, stream>>>(
        h1b, 512, W2t, 512, g2, b2, x, out, 512);
}